// Round 3
// baseline (259.172 us; speedup 1.0000x reference)
//
#include <hip/hip_runtime.h>

typedef __bf16 bf16;
typedef __bf16 bf16x8 __attribute__((ext_vector_type(8)));
typedef float  f32x4  __attribute__((ext_vector_type(4)));
typedef float  f32x16 __attribute__((ext_vector_type(16)));

static constexpr int CB = 2;     // batch
static constexpr int CS = 2048;  // seq
static constexpr int CD = 512;   // model dim
static constexpr int CH = 8;     // heads
static constexpr int CDK = 64;   // head dim
static constexpr int NROWS = CB * CH * CS;        // 32768 attention rows
static constexpr size_t NT = (size_t)CB * CS * CD; // 2,097,152 elements per tensor

__device__ __forceinline__ f32x4 mfma16(bf16x8 a, bf16x8 b, f32x4 c) {
    return __builtin_amdgcn_mfma_f32_16x16x32_bf16(a, b, c, 0, 0, 0);
}
__device__ __forceinline__ f32x16 mfma32(bf16x8 a, bf16x8 b, f32x16 c) {
    return __builtin_amdgcn_mfma_f32_32x32x16_bf16(a, b, c, 0, 0, 0);
}

__device__ __forceinline__ bf16x8 cvt8(const float* __restrict__ p) {
    float4 x0 = *reinterpret_cast<const float4*>(p);
    float4 x1 = *reinterpret_cast<const float4*>(p + 4);
    bf16x8 r;
    r[0] = (bf16)x0.x; r[1] = (bf16)x0.y; r[2] = (bf16)x0.z; r[3] = (bf16)x0.w;
    r[4] = (bf16)x1.x; r[5] = (bf16)x1.y; r[6] = (bf16)x1.z; r[7] = (bf16)x1.w;
    return r;
}

struct PPtrs {
    const float* A[6];
    const float* W[6];
    const float* bias[6];
    bf16* dst[6];
    int mode[6];   // 0: [B,H,S,DK]   1: [B,H,DK,S] (transposed V)
};

// ---- merged projection GEMM: C[m,n] = sum_k A[m,k]*W[n,k] + bias[n] ----
__global__ __launch_bounds__(256) void proj_kernel(PPtrs P) {
    __shared__ bf16 aL[64][72];
    __shared__ bf16 bL[64][72];
    const int z = blockIdx.z;
    const float* __restrict__ A    = P.A[z];
    const float* __restrict__ Bt   = P.W[z];
    const float* __restrict__ bias = P.bias[z];
    bf16* __restrict__ dst = P.dst[z];
    const int mode = P.mode[z];

    const int m0 = blockIdx.x * 64, n0 = blockIdx.y * 64;
    const int tid = threadIdx.x;
    const int lane = tid & 63, w = tid >> 6;
    const int wm = w >> 1, wn = w & 1;
    const int l16 = lane & 15, lhi = lane >> 4;
    const int srow = tid >> 2, sk = (tid & 3) * 16;

    f32x4 acc[2][2] = {};

    for (int k0 = 0; k0 < 512; k0 += 64) {
        __syncthreads();
        *reinterpret_cast<bf16x8*>(&aL[srow][sk])     = cvt8(A + (size_t)(m0 + srow) * 512 + k0 + sk);
        *reinterpret_cast<bf16x8*>(&aL[srow][sk + 8]) = cvt8(A + (size_t)(m0 + srow) * 512 + k0 + sk + 8);
        *reinterpret_cast<bf16x8*>(&bL[srow][sk])     = cvt8(Bt + (size_t)(n0 + srow) * 512 + k0 + sk);
        *reinterpret_cast<bf16x8*>(&bL[srow][sk + 8]) = cvt8(Bt + (size_t)(n0 + srow) * 512 + k0 + sk + 8);
        __syncthreads();

        #pragma unroll
        for (int ks = 0; ks < 2; ++ks) {
            bf16x8 af0 = *reinterpret_cast<const bf16x8*>(&aL[wm*32 +      l16][ks*32 + lhi*8]);
            bf16x8 af1 = *reinterpret_cast<const bf16x8*>(&aL[wm*32 + 16 + l16][ks*32 + lhi*8]);
            bf16x8 bg0 = *reinterpret_cast<const bf16x8*>(&bL[wn*32 +      l16][ks*32 + lhi*8]);
            bf16x8 bg1 = *reinterpret_cast<const bf16x8*>(&bL[wn*32 + 16 + l16][ks*32 + lhi*8]);
            acc[0][0] = mfma16(af0, bg0, acc[0][0]);
            acc[0][1] = mfma16(af0, bg1, acc[0][1]);
            acc[1][0] = mfma16(af1, bg0, acc[1][0]);
            acc[1][1] = mfma16(af1, bg1, acc[1][1]);
        }
    }

    #pragma unroll
    for (int ms = 0; ms < 2; ++ms)
    #pragma unroll
    for (int ns = 0; ns < 2; ++ns) {
        const int col = n0 + wn*32 + ns*16 + l16;
        const float bv = bias[col];
        const int hh = col >> 6, dk = col & 63;
        #pragma unroll
        for (int i = 0; i < 4; ++i) {
            const int m = m0 + wm*32 + ms*16 + lhi*4 + i;
            const float v = acc[ms][ns][i] + bv;
            const int b = m >> 11, s = m & 2047;
            if (mode == 0)
                dst[(((size_t)(b*CH + hh)) * CS + s) * CDK + dk] = (bf16)v;
            else
                dst[(((size_t)(b*CH + hh)) * CDK + dk) * CS + s] = (bf16)v;
        }
    }
}

// ---- merged output GEMM ----
__global__ __launch_bounds__(256) void oproj_kernel(
    const bf16* __restrict__ Xr, const bf16* __restrict__ Xp,
    const float* __restrict__ Wo, const float* __restrict__ bo,
    float* __restrict__ out)
{
    __shared__ bf16 aL[64][72];
    __shared__ bf16 bL[64][72];
    const bf16* __restrict__ A = blockIdx.z ? Xp : Xr;
    float* __restrict__ dst = out + (size_t)blockIdx.z * NT;

    const int m0 = blockIdx.x * 64, n0 = blockIdx.y * 64;
    const int tid = threadIdx.x;
    const int lane = tid & 63, w = tid >> 6;
    const int wm = w >> 1, wn = w & 1;
    const int l16 = lane & 15, lhi = lane >> 4;
    const int srow = tid >> 2, sk = (tid & 3) * 16;

    f32x4 acc[2][2] = {};

    for (int k0 = 0; k0 < 512; k0 += 64) {
        __syncthreads();
        *reinterpret_cast<bf16x8*>(&aL[srow][sk]) =
            *reinterpret_cast<const bf16x8*>(A + (size_t)(m0 + srow) * 512 + k0 + sk);
        *reinterpret_cast<bf16x8*>(&aL[srow][sk + 8]) =
            *reinterpret_cast<const bf16x8*>(A + (size_t)(m0 + srow) * 512 + k0 + sk + 8);
        *reinterpret_cast<bf16x8*>(&bL[srow][sk])     = cvt8(Wo + (size_t)(n0 + srow) * 512 + k0 + sk);
        *reinterpret_cast<bf16x8*>(&bL[srow][sk + 8]) = cvt8(Wo + (size_t)(n0 + srow) * 512 + k0 + sk + 8);
        __syncthreads();

        #pragma unroll
        for (int ks = 0; ks < 2; ++ks) {
            bf16x8 af0 = *reinterpret_cast<const bf16x8*>(&aL[wm*32 +      l16][ks*32 + lhi*8]);
            bf16x8 af1 = *reinterpret_cast<const bf16x8*>(&aL[wm*32 + 16 + l16][ks*32 + lhi*8]);
            bf16x8 bg0 = *reinterpret_cast<const bf16x8*>(&bL[wn*32 +      l16][ks*32 + lhi*8]);
            bf16x8 bg1 = *reinterpret_cast<const bf16x8*>(&bL[wn*32 + 16 + l16][ks*32 + lhi*8]);
            acc[0][0] = mfma16(af0, bg0, acc[0][0]);
            acc[0][1] = mfma16(af0, bg1, acc[0][1]);
            acc[1][0] = mfma16(af1, bg0, acc[1][0]);
            acc[1][1] = mfma16(af1, bg1, acc[1][1]);
        }
    }

    #pragma unroll
    for (int ms = 0; ms < 2; ++ms)
    #pragma unroll
    for (int ns = 0; ns < 2; ++ns) {
        const int col = n0 + wn*32 + ns*16 + l16;
        const float bv = bo[col];
        #pragma unroll
        for (int i = 0; i < 4; ++i) {
            const int m = m0 + wm*32 + ms*16 + lhi*4 + i;
            dst[(size_t)m * 512 + col] = acc[ms][ns][i] + bv;
        }
    }
}

// ---- flash attention, swapped-operand 32x32 MFMA, in-register softmax ----
// 1D grid: 16 qtiles * 16 bh * nsp, XCD-grouped. 256 thr (4 waves), 32 q/wave.
// S^T[key][q] = K*Q^T; fixed softmax max (scores in [0,~1.7]); P assembled
// in-register via v_cvt_pk_bf16_f32 + v_permlane32_swap_b32; O^T[d][q] out.
__global__ __launch_bounds__(256, 3) void attn_kernel(
    const bf16* __restrict__ Qr, const bf16* __restrict__ Qp,
    const bf16* __restrict__ Kr, const bf16* __restrict__ Kp,
    const bf16* __restrict__ Vtr, const bf16* __restrict__ Vtp,
    const int* __restrict__ mask, int lognsp,
    float* __restrict__ POR, float* __restrict__ POP, float* __restrict__ PLs)
{
    __shared__ uint4 kRr[512], kRp[512], vRr[512], vRp[512];  // 32KB, swizzled

    const int F = blockIdx.x;
    const int qt = (F >> 3) & 15;
    const int g  = (F & 7) + ((F >> 7) << 3);      // XCD-grouped (bh,z)
    const int bh = g >> lognsp, z = g & ((1 << lognsp) - 1);
    const int Lkv = CS >> lognsp;
    const int kvbase = z * Lkv;
    const int b = bh >> 3;
    const size_t base = (size_t)bh * CS * CDK;

    const int tid = threadIdx.x, lane = tid & 63, w = tid >> 6;
    const int l32 = lane & 31, hi = lane >> 5;
    const int q0 = qt * 128 + w * 32;

    // Q fragments (B-operand): col=l32=q, k = ks*16 + hi*8 + j
    bf16x8 qr[4], qp[4];
    #pragma unroll
    for (int ks = 0; ks < 4; ++ks) {
        qr[ks] = *reinterpret_cast<const bf16x8*>(&Qr[base + (size_t)(q0 + l32)*CDK + ks*16 + hi*8]);
        qp[ks] = *reinterpret_cast<const bf16x8*>(&Qp[base + (size_t)(q0 + l32)*CDK + ks*16 + hi*8]);
    }

    f32x16 oR[2] = {}, oP[2] = {};
    float lsum = 0.f;

    const int srow = tid >> 2;          // staging row 0..63
    const int sc = (tid & 3) * 2;       // 2 chunks of 16B
    const int swr = srow & 7;

    const int* __restrict__ mrow = mask + b*CS + kvbase;

    for (int kv0 = 0; kv0 < Lkv; kv0 += 64) {
        const int kvg = kvbase + kv0;
        __syncthreads();
        {
            const uint4* gkr = reinterpret_cast<const uint4*>(&Kr [base + (size_t)(kvg + srow)*CDK + sc*8]);
            const uint4* gkp = reinterpret_cast<const uint4*>(&Kp [base + (size_t)(kvg + srow)*CDK + sc*8]);
            const uint4* gvr = reinterpret_cast<const uint4*>(&Vtr[base + (size_t)srow*CS + kvg + sc*8]);
            const uint4* gvp = reinterpret_cast<const uint4*>(&Vtp[base + (size_t)srow*CS + kvg + sc*8]);
            const int i0 = srow*8 + ( sc      ^ swr);
            const int i1 = srow*8 + ((sc + 1) ^ swr);
            kRr[i0] = gkr[0]; kRr[i1] = gkr[1];
            kRp[i0] = gkp[0]; kRp[i1] = gkp[1];
            vRr[i0] = gvr[0]; vRr[i1] = gvr[1];
            vRp[i0] = gvp[0]; vRp[i1] = gvp[1];
        }
        const unsigned long long m64 = __ballot(mrow[kv0 + lane] != 0);
        __syncthreads();

        const unsigned int msub[2] = { (unsigned int)m64, (unsigned int)(m64 >> 32) };

        #pragma unroll
        for (int kb = 0; kb < 2; ++kb) {
            f32x16 aR = {}, aP = {};
            #pragma unroll
            for (int ks = 0; ks < 4; ++ks) {
                const int row = kb*32 + l32;
                const int ci = row*8 + ((ks*2 + hi) ^ (l32 & 7));
                bf16x8 kr8 = __builtin_bit_cast(bf16x8, kRr[ci]);
                bf16x8 kp8 = __builtin_bit_cast(bf16x8, kRp[ci]);
                uint4 tq = __builtin_bit_cast(uint4, qp[ks]);
                tq.x ^= 0x80008000u; tq.y ^= 0x80008000u;
                tq.z ^= 0x80008000u; tq.w ^= 0x80008000u;
                bf16x8 qn = __builtin_bit_cast(bf16x8, tq);  // -qp exact
                aR = mfma32(kr8, qr[ks], aR);
                aR = mfma32(kp8, qn,     aR);
                aP = mfma32(kr8, qp[ks], aP);
                aP = mfma32(kp8, qr[ks], aP);
            }
            // p = exp(|s|/8 - 4) = exp2(mag*0.18033688 - 5.77078016); masked -> 0
            const unsigned int sh = msub[kb] >> (hi * 4);
            float p[16];
            float ps = 0.f;
            #pragma unroll
            for (int r = 0; r < 16; ++r) {
                const int pos = (r & 3) + 8 * (r >> 2);   // key-in-32 = pos + 4*hi
                const float sr = aR[r], sp = aP[r];
                const float mag = sqrtf(fmaf(sr, sr, sp * sp));
                float pv = __builtin_amdgcn_exp2f(fmaf(mag, 0.18033688f, -5.77078016f));
                pv = (sh & (1u << pos)) ? pv : 0.0f;
                p[r] = pv;
                ps += pv;
            }
            lsum += ps;

            // pack pairs to bf16 and half-swap into PV B-fragments
            unsigned int u[8];
            #pragma unroll
            for (int i = 0; i < 8; ++i)
                asm("v_cvt_pk_bf16_f32 %0, %1, %2" : "=v"(u[i]) : "v"(p[2*i]), "v"(p[2*i+1]));
            asm volatile("v_permlane32_swap_b32 %0, %1" : "+v"(u[0]), "+v"(u[2]));
            asm volatile("v_permlane32_swap_b32 %0, %1" : "+v"(u[1]), "+v"(u[3]));
            asm volatile("v_permlane32_swap_b32 %0, %1" : "+v"(u[4]), "+v"(u[6]));
            asm volatile("v_permlane32_swap_b32 %0, %1" : "+v"(u[5]), "+v"(u[7]));

            #pragma unroll
            for (int kspv = 0; kspv < 2; ++kspv) {
                uint4 fw;
                fw.x = u[kspv*4 + 0]; fw.y = u[kspv*4 + 1];
                fw.z = u[kspv*4 + 2]; fw.w = u[kspv*4 + 3];
                const bf16x8 pf = __builtin_bit_cast(bf16x8, fw);
                #pragma unroll
                for (int dt = 0; dt < 2; ++dt) {
                    const int vrow = dt*32 + l32;
                    const int ci = vrow*8 + ((kb*4 + kspv*2 + hi) ^ (l32 & 7));
                    oR[dt] = mfma32(__builtin_bit_cast(bf16x8, vRr[ci]), pf, oR[dt]);
                    oP[dt] = mfma32(__builtin_bit_cast(bf16x8, vRp[ci]), pf, oP[dt]);
                }
            }
        }
    }

    // epilogue
    lsum += __shfl_xor(lsum, 32);
    const int q = q0 + l32;
    if (lane < 32)
        PLs[(size_t)z * NROWS + bh * CS + q] = lsum;

    const size_t obase = ((size_t)(z * 16 + bh) * 64) * CS;   // [z][bh][d][q]
    #pragma unroll
    for (int dt = 0; dt < 2; ++dt)
        #pragma unroll
        for (int r = 0; r < 16; ++r) {
            const int d = dt*32 + (r & 3) + 8*(r >> 2) + 4*hi;
            POR[obase + (size_t)d * CS + q] = oR[dt][r];
            POP[obase + (size_t)d * CS + q] = oP[dt][r];
        }
}

// ---- combine KV-split partials, normalize, transpose, write [B,S,D] bf16 ----
// grid (32 q-chunks of 64, 16 bh). POR layout [z][bh][d=64][q=2048].
__global__ __launch_bounds__(256) void merge_kernel(
    const float* __restrict__ POR, const float* __restrict__ POP,
    const float* __restrict__ PLs, int nsp,
    bf16* __restrict__ Xr, bf16* __restrict__ Xp)
{
    __shared__ float lsh[64];
    __shared__ bf16 bufR[64][72], bufP[64][72];

    const int qb = blockIdx.x * 64, bh = blockIdx.y;
    const int t = threadIdx.x;
    const int b = bh >> 3, h = bh & 7;

    if (t < 64) {
        float s = 0.f;
        for (int zz = 0; zz < nsp; ++zz)
            s += PLs[(size_t)zz * NROWS + bh * CS + qb + t];
        lsh[t] = 1.f / s;
    }
    __syncthreads();

    const int dlo = t >> 4, qi = (t & 15) * 4;
    f32x4 aR[4] = {}, aP[4] = {};
    for (int zz = 0; zz < nsp; ++zz) {
        const size_t zb = ((size_t)(zz * 16 + bh) * 64) * CS;
        #pragma unroll
        for (int c = 0; c < 4; ++c) {
            const size_t off = zb + (size_t)(dlo + c*16) * CS + qb + qi;
            aR[c] += *reinterpret_cast<const f32x4*>(&POR[off]);
            aP[c] += *reinterpret_cast<const f32x4*>(&POP[off]);
        }
    }
    #pragma unroll
    for (int c = 0; c < 4; ++c)
        #pragma unroll
        for (int j = 0; j < 4; ++j) {
            const float inv = lsh[qi + j];
            bufR[qi + j][dlo + c*16] = (bf16)(aR[c][j] * inv);
            bufP[qi + j][dlo + c*16] = (bf16)(aP[c][j] * inv);
        }
    __syncthreads();

    const int q = t >> 2, ch = t & 3;
    const size_t xoff = ((size_t)(b * CS + qb + q)) * CD + h * CDK + ch * 16;
    *reinterpret_cast<bf16x8*>(&Xr[xoff])     = *reinterpret_cast<const bf16x8*>(&bufR[q][ch*16]);
    *reinterpret_cast<bf16x8*>(&Xr[xoff + 8]) = *reinterpret_cast<const bf16x8*>(&bufR[q][ch*16 + 8]);
    *reinterpret_cast<bf16x8*>(&Xp[xoff])     = *reinterpret_cast<const bf16x8*>(&bufP[q][ch*16]);
    *reinterpret_cast<bf16x8*>(&Xp[xoff + 8]) = *reinterpret_cast<const bf16x8*>(&bufP[q][ch*16 + 8]);
}

extern "C" void kernel_launch(void* const* d_in, const int* in_sizes, int n_in,
                              void* d_out, int out_size, void* d_ws, size_t ws_size,
                              hipStream_t stream) {
    const float* q_r = (const float*)d_in[0];
    const float* k_r = (const float*)d_in[1];
    const float* v_r = (const float*)d_in[2];
    const float* q_p = (const float*)d_in[3];
    const float* k_p = (const float*)d_in[4];
    const float* v_p = (const float*)d_in[5];
    const int*  mask = (const int*)d_in[6];
    const float* Wq = (const float*)d_in[7];  const float* bq = (const float*)d_in[8];
    const float* Wk = (const float*)d_in[9];  const float* bk = (const float*)d_in[10];
    const float* Wv = (const float*)d_in[11]; const float* bv = (const float*)d_in[12];
    const float* Wo = (const float*)d_in[13]; const float* bo = (const float*)d_in[14];
    float* out = (float*)d_out;

    bf16* ws = (bf16*)d_ws;
    bf16 *Qr = ws,        *Qp = Qr + NT;
    bf16 *Kr = Qp + NT,   *Kp = Kr + NT;
    bf16 *Vtr = Kp + NT,  *Vtp = Vtr + NT;
    bf16 *Xr = Vtp + NT,  *Xp = Xr + NT;     // 8 * NT * 2B = 33.55 MB
    float* POR = (float*)(ws + 8 * NT);

    const size_t fixed = 8 * NT * sizeof(bf16);
    const size_t per_split = (size_t)NROWS * 64 * 4 * 2 + (size_t)NROWS * 4;
    int nsp, lognsp;
    if (ws_size >= fixed + 4 * per_split)      { nsp = 4; lognsp = 2; }
    else if (ws_size >= fixed + 2 * per_split) { nsp = 2; lognsp = 1; }
    else                                       { nsp = 1; lognsp = 0; }
    float* POP = POR + (size_t)nsp * NROWS * 64;
    float* PLs = POP + (size_t)nsp * NROWS * 64;

    dim3 blk(256);

    PPtrs P;
    P.A[0]=q_r; P.A[1]=q_p; P.A[2]=k_r; P.A[3]=k_p; P.A[4]=v_r; P.A[5]=v_p;
    P.W[0]=Wq;  P.W[1]=Wq;  P.W[2]=Wk;  P.W[3]=Wk;  P.W[4]=Wv;  P.W[5]=Wv;
    P.bias[0]=bq; P.bias[1]=bq; P.bias[2]=bk; P.bias[3]=bk; P.bias[4]=bv; P.bias[5]=bv;
    P.dst[0]=Qr; P.dst[1]=Qp; P.dst[2]=Kr; P.dst[3]=Kp; P.dst[4]=Vtr; P.dst[5]=Vtp;
    P.mode[0]=0; P.mode[1]=0; P.mode[2]=0; P.mode[3]=0; P.mode[4]=1; P.mode[5]=1;

    proj_kernel<<<dim3(64, 8, 6), blk, 0, stream>>>(P);

    attn_kernel<<<dim3(256 * nsp), blk, 0, stream>>>(Qr, Qp, Kr, Kp, Vtr, Vtp,
                                                     mask, lognsp, POR, POP, PLs);

    merge_kernel<<<dim3(32, 16), blk, 0, stream>>>(POR, POP, PLs, nsp, Xr, Xp);

    oproj_kernel<<<dim3(64, 8, 2), blk, 0, stream>>>(Xr, Xp, Wo, bo, out);
}

// Round 4
// 186.737 us; speedup vs baseline: 1.3879x; 1.3879x over previous
//
#include <hip/hip_runtime.h>

typedef __bf16 bf16;
typedef __bf16 bf16x8 __attribute__((ext_vector_type(8)));
typedef float  f32x4  __attribute__((ext_vector_type(4)));

static constexpr int CB = 2;     // batch
static constexpr int CS = 2048;  // seq
static constexpr int CD = 512;   // model dim
static constexpr int CH = 8;     // heads
static constexpr int CDK = 64;   // head dim
static constexpr int NROWS = CB * CH * CS;         // 32768 attention rows
static constexpr size_t NT = (size_t)CB * CS * CD; // 2,097,152 elements per tensor

__device__ __forceinline__ f32x4 mfma16(bf16x8 a, bf16x8 b, f32x4 c) {
    return __builtin_amdgcn_mfma_f32_16x16x32_bf16(a, b, c, 0, 0, 0);
}

__device__ __forceinline__ bf16x8 cvt8(const float* __restrict__ p) {
    float4 x0 = *reinterpret_cast<const float4*>(p);
    float4 x1 = *reinterpret_cast<const float4*>(p + 4);
    bf16x8 r;
    r[0] = (bf16)x0.x; r[1] = (bf16)x0.y; r[2] = (bf16)x0.z; r[3] = (bf16)x0.w;
    r[4] = (bf16)x1.x; r[5] = (bf16)x1.y; r[6] = (bf16)x1.z; r[7] = (bf16)x1.w;
    return r;
}

__device__ __forceinline__ void gload16(const void* g, void* l) {
    __builtin_amdgcn_global_load_lds(
        (const __attribute__((address_space(1))) void*)g,
        (__attribute__((address_space(3))) void*)l, 16, 0, 0);
}

struct PPtrs {
    const float* A[6];
    const float* W[6];
    const float* bias[6];
    bf16* dst[6];
    int mode[6];   // 0: [B,H,S,DK]   1: [B,H,DK,S] (transposed V)
};

// ---- merged projection GEMM, 128x128 tile: C[m,n] = sum_k A[m,k]*W[n,k] + bias[n] ----
// M=4096, N=512, K=512. grid (32, 4, 6). 4 waves, each 64x64 out.
__global__ __launch_bounds__(256) void proj_kernel(PPtrs P) {
    __shared__ bf16 aL[128][72];   // 144B stride, conflict-free (measured r2 pattern)
    __shared__ bf16 bL[128][72];
    const int z = blockIdx.z;
    const float* __restrict__ A    = P.A[z];
    const float* __restrict__ Bt   = P.W[z];
    const float* __restrict__ bias = P.bias[z];
    bf16* __restrict__ dst = P.dst[z];
    const int mode = P.mode[z];

    const int m0 = blockIdx.x * 128, n0 = blockIdx.y * 128;
    const int tid = threadIdx.x;
    const int lane = tid & 63, w = tid >> 6;
    const int wr = w >> 1, wc = w & 1;
    const int l16 = lane & 15, lhi = lane >> 4;
    const int srow = tid >> 1, sk = (tid & 1) * 32;

    f32x4 acc[4][4] = {};

    for (int k0 = 0; k0 < 512; k0 += 64) {
        __syncthreads();
        #pragma unroll
        for (int c = 0; c < 4; ++c) {
            *reinterpret_cast<bf16x8*>(&aL[srow][sk + c*8]) =
                cvt8(A + (size_t)(m0 + srow) * 512 + k0 + sk + c*8);
            *reinterpret_cast<bf16x8*>(&bL[srow][sk + c*8]) =
                cvt8(Bt + (size_t)(n0 + srow) * 512 + k0 + sk + c*8);
        }
        __syncthreads();

        #pragma unroll
        for (int ks = 0; ks < 2; ++ks) {
            bf16x8 af[4], bg[4];
            #pragma unroll
            for (int ms = 0; ms < 4; ++ms)
                af[ms] = *reinterpret_cast<const bf16x8*>(&aL[wr*64 + ms*16 + l16][ks*32 + lhi*8]);
            #pragma unroll
            for (int ns = 0; ns < 4; ++ns)
                bg[ns] = *reinterpret_cast<const bf16x8*>(&bL[wc*64 + ns*16 + l16][ks*32 + lhi*8]);
            #pragma unroll
            for (int ms = 0; ms < 4; ++ms)
                #pragma unroll
                for (int ns = 0; ns < 4; ++ns)
                    acc[ms][ns] = mfma16(af[ms], bg[ns], acc[ms][ns]);
        }
    }

    #pragma unroll
    for (int ms = 0; ms < 4; ++ms)
    #pragma unroll
    for (int ns = 0; ns < 4; ++ns) {
        const int col = n0 + wc*64 + ns*16 + l16;
        const float bv = bias[col];
        const int hh = col >> 6, dk = col & 63;
        #pragma unroll
        for (int i = 0; i < 4; ++i) {
            const int m = m0 + wr*64 + ms*16 + lhi*4 + i;
            const float v = acc[ms][ns][i] + bv;
            const int b = m >> 11, s = m & 2047;
            if (mode == 0)
                dst[(((size_t)(b*CH + hh)) * CS + s) * CDK + dk] = (bf16)v;
            else
                dst[(((size_t)(b*CH + hh)) * CDK + dk) * CS + s] = (bf16)v;
        }
    }
}

// ---- output GEMM, 128x128 tile: out[z][m,n] = sum_k X[z][m,k]*Wo[n,k] + bo[n] ----
__global__ __launch_bounds__(256) void oproj_kernel(
    const bf16* __restrict__ Xr, const bf16* __restrict__ Xp,
    const float* __restrict__ Wo, const float* __restrict__ bo,
    float* __restrict__ out)
{
    __shared__ bf16 aL[128][72];
    __shared__ bf16 bL[128][72];
    const bf16* __restrict__ A = blockIdx.z ? Xp : Xr;
    float* __restrict__ dst = out + (size_t)blockIdx.z * NT;

    const int m0 = blockIdx.x * 128, n0 = blockIdx.y * 128;
    const int tid = threadIdx.x;
    const int lane = tid & 63, w = tid >> 6;
    const int wr = w >> 1, wc = w & 1;
    const int l16 = lane & 15, lhi = lane >> 4;
    const int srow = tid >> 1, sk = (tid & 1) * 32;

    f32x4 acc[4][4] = {};

    for (int k0 = 0; k0 < 512; k0 += 64) {
        __syncthreads();
        #pragma unroll
        for (int c = 0; c < 4; ++c) {
            *reinterpret_cast<bf16x8*>(&aL[srow][sk + c*8]) =
                *reinterpret_cast<const bf16x8*>(A + (size_t)(m0 + srow) * 512 + k0 + sk + c*8);
            *reinterpret_cast<bf16x8*>(&bL[srow][sk + c*8]) =
                cvt8(Wo + (size_t)(n0 + srow) * 512 + k0 + sk + c*8);
        }
        __syncthreads();

        #pragma unroll
        for (int ks = 0; ks < 2; ++ks) {
            bf16x8 af[4], bg[4];
            #pragma unroll
            for (int ms = 0; ms < 4; ++ms)
                af[ms] = *reinterpret_cast<const bf16x8*>(&aL[wr*64 + ms*16 + l16][ks*32 + lhi*8]);
            #pragma unroll
            for (int ns = 0; ns < 4; ++ns)
                bg[ns] = *reinterpret_cast<const bf16x8*>(&bL[wc*64 + ns*16 + l16][ks*32 + lhi*8]);
            #pragma unroll
            for (int ms = 0; ms < 4; ++ms)
                #pragma unroll
                for (int ns = 0; ns < 4; ++ns)
                    acc[ms][ns] = mfma16(af[ms], bg[ns], acc[ms][ns]);
        }
    }

    #pragma unroll
    for (int ms = 0; ms < 4; ++ms)
    #pragma unroll
    for (int ns = 0; ns < 4; ++ns) {
        const int col = n0 + wc*64 + ns*16 + l16;
        const float bv = bo[col];
        #pragma unroll
        for (int i = 0; i < 4; ++i) {
            const int m = m0 + wr*64 + ms*16 + lhi*4 + i;
            dst[(size_t)m * 512 + col] = acc[ms][ns][i] + bv;
        }
    }
}

// ---- flash attention: QBLK=128 (32 q/wave, 2 subtiles), KV tile 64, dbuf gload_lds ----
// grid 16qt*16bh*nsp 1D XCD-swizzled. LDS = 64KB K/V dbuf + 16KB pL = 80KB (2 blk/CU).
__global__ __launch_bounds__(256) void attn_kernel(
    const bf16* __restrict__ Qr, const bf16* __restrict__ Qp,
    const bf16* __restrict__ Kr, const bf16* __restrict__ Kp,
    const bf16* __restrict__ Vtr, const bf16* __restrict__ Vtp,
    const int* __restrict__ mask, int lognsp,
    float* __restrict__ POR, float* __restrict__ POP, float* __restrict__ PLs)
{
    __shared__ uint4 stg[2][4][512];   // [buf][tensor Kr,Kp,Vtr,Vtp][row*8+slot] 64KB
    __shared__ bf16 pL[4][32][64];     // per-wave P, XOR-swizzled, 16KB

    const int F = blockIdx.x;
    const int qt = (F >> 3) & 15;
    const int g  = (F & 7) | ((F >> 7) << 3);     // (bh,z) groups pinned per XCD
    const int bh = g >> lognsp, z = g & ((1 << lognsp) - 1);
    const int Lkv = CS >> lognsp, kvbase = z * Lkv;
    const int nt = Lkv >> 6;
    const int b = bh >> 3;
    const size_t base = (size_t)bh * CS * CDK;

    const int tid = threadIdx.x, lane = tid & 63, w = tid >> 6;
    const int l16 = lane & 15, lhi = lane >> 4;
    const int q0 = qt * 128 + w * 32;

    // Q fragments for 2 subtiles: A-frag row = l16, k = ks*32 + lhi*8 + j
    bf16x8 qrf[2][2], qpf[2][2], qnf[2][2];
    #pragma unroll
    for (int ms = 0; ms < 2; ++ms)
        #pragma unroll
        for (int ks = 0; ks < 2; ++ks) {
            const size_t qoff = base + (size_t)(q0 + ms*16 + l16) * CDK + ks*32 + lhi*8;
            qrf[ms][ks] = *reinterpret_cast<const bf16x8*>(&Qr[qoff]);
            qpf[ms][ks] = *reinterpret_cast<const bf16x8*>(&Qp[qoff]);
            uint4 t = __builtin_bit_cast(uint4, qpf[ms][ks]);
            t.x ^= 0x80008000u; t.y ^= 0x80008000u; t.z ^= 0x80008000u; t.w ^= 0x80008000u;
            qnf[ms][ks] = __builtin_bit_cast(bf16x8, t);   // -qp exact
        }

    f32x4 oR[2][4] = {}, oP[2][4] = {};
    float lpart[2][4] = {};

    // staging: wave w owns tensor w; per-lane pre-swizzled global source,
    // linear LDS dest (slot l%8 holds global chunk (l%8)^(l/8))
    const int srowL = lane >> 3, slotL = lane & 7;
    const int chunkL = slotL ^ srowL;
    const char* gsrc;
    size_t laneoff, iStride, tStride;
    if (w == 0)      gsrc = (const char*)Kr;
    else if (w == 1) gsrc = (const char*)Kp;
    else if (w == 2) gsrc = (const char*)Vtr;
    else             gsrc = (const char*)Vtp;
    if (w < 2) {
        laneoff = base*2 + (size_t)(kvbase + srowL) * 128 + chunkL*16;
        iStride = 1024;  tStride = 8192;
    } else {
        laneoff = base*2 + (size_t)srowL * (CS*2) + (size_t)kvbase*2 + chunkL*16;
        iStride = 8 * CS * 2;  tStride = 128;
    }
    const char* gp = gsrc + laneoff;

    auto stage = [&](int bi, int t) {
        const char* p = gp + (size_t)t * tStride;
        uint4* ldst = &stg[bi][w][0];
        #pragma unroll
        for (int i = 0; i < 8; ++i)
            gload16(p + i*iStride, ldst + i*64);
    };

    // pL swizzle: injective on stride-1 (reads) and stride-4 (writes) row groups
    auto fswz = [](int r) { return (r & 7) ^ (((r >> 3) & 1) << 1); };

    stage(0, 0);
    asm volatile("s_waitcnt vmcnt(0)" ::: "memory");
    __syncthreads();

    for (int t = 0; t < nt; ++t) {
        if (t + 1 < nt) stage((t + 1) & 1, t + 1);

        const int bi = t & 1;
        const int kvg = kvbase + t * 64;
        const unsigned long long m64 = __ballot(mask[b*CS + kvg + lane] != 0);
        const uint4* kTr = &stg[bi][0][0];
        const uint4* kTp = &stg[bi][1][0];
        const uint4* vTr = &stg[bi][2][0];
        const uint4* vTp = &stg[bi][3][0];

        float sc[2][4][4];
        #pragma unroll
        for (int kb = 0; kb < 4; ++kb) {
            const int krow = kb*16 + l16;
            bf16x8 kr8[2], kp8[2];
            #pragma unroll
            for (int ks = 0; ks < 2; ++ks) {
                const int ci = krow*8 + ((ks*4 + lhi) ^ (krow & 7));
                kr8[ks] = __builtin_bit_cast(bf16x8, kTr[ci]);
                kp8[ks] = __builtin_bit_cast(bf16x8, kTp[ci]);
            }
            const unsigned int keep = ((unsigned int)(m64 >> (kb*16)) >> l16) & 1u;
            #pragma unroll
            for (int ms = 0; ms < 2; ++ms) {
                f32x4 aR = {}, aP = {};
                #pragma unroll
                for (int ks = 0; ks < 2; ++ks) {
                    aR = mfma16(qrf[ms][ks], kr8[ks], aR);
                    aR = mfma16(qnf[ms][ks], kp8[ks], aR);
                    aP = mfma16(qrf[ms][ks], kp8[ks], aP);
                    aP = mfma16(qpf[ms][ks], kr8[ks], aP);
                }
                #pragma unroll
                for (int i = 0; i < 4; ++i) {
                    const float sr = aR[i], sp = aP[i];
                    const float mag = __builtin_amdgcn_sqrtf(fmaf(sr, sr, sp*sp));
                    float p = __builtin_amdgcn_exp2f(fmaf(mag, 0.18033688f, -5.77078016f));
                    p = keep ? p : 0.0f;
                    sc[ms][kb][i] = p;
                    lpart[ms][i] += p;
                }
            }
        }

        // write P (both subtiles) to per-wave swizzled pL
        bf16* pB = &pL[w][0][0];
        #pragma unroll
        for (int ms = 0; ms < 2; ++ms)
            #pragma unroll
            for (int i = 0; i < 4; ++i) {
                const int row = ms*16 + lhi*4 + i;
                const int sw = fswz(row) << 3;
                #pragma unroll
                for (int kb = 0; kb < 4; ++kb)
                    pB[row*64 + ((kb*16 + l16) ^ sw)] = (bf16)sc[ms][kb][i];
            }
        asm volatile("s_waitcnt lgkmcnt(0)" ::: "memory");
        __builtin_amdgcn_sched_barrier(0);

        // PV: V-frags shared across both subtiles
        const uint4* pW = reinterpret_cast<const uint4*>(&pL[w][0][0]);
        #pragma unroll
        for (int ks = 0; ks < 2; ++ks) {
            bf16x8 pf[2];
            #pragma unroll
            for (int ms = 0; ms < 2; ++ms) {
                const int prow = ms*16 + l16;
                pf[ms] = __builtin_bit_cast(bf16x8, pW[prow*8 + ((ks*4 + lhi) ^ fswz(prow))]);
            }
            #pragma unroll
            for (int d = 0; d < 4; ++d) {
                const int vrow = d*16 + l16;
                const int ci = vrow*8 + ((ks*4 + lhi) ^ (vrow & 7));
                const bf16x8 v8r = __builtin_bit_cast(bf16x8, vTr[ci]);
                const bf16x8 v8p = __builtin_bit_cast(bf16x8, vTp[ci]);
                #pragma unroll
                for (int ms = 0; ms < 2; ++ms) {
                    oR[ms][d] = mfma16(pf[ms], v8r, oR[ms][d]);
                    oP[ms][d] = mfma16(pf[ms], v8p, oP[ms][d]);
                }
            }
        }

        if (t + 1 < nt) __syncthreads();
    }

    // epilogue: reduce l across the 16-lane row group, store partials [z][row][64]
    #pragma unroll
    for (int ms = 0; ms < 2; ++ms)
        #pragma unroll
        for (int i = 0; i < 4; ++i) {
            float v = lpart[ms][i];
            v += __shfl_xor(v, 1); v += __shfl_xor(v, 2);
            v += __shfl_xor(v, 4); v += __shfl_xor(v, 8);
            lpart[ms][i] = v;
        }
    const int r0 = bh * CS + q0;
    if (l16 == 0) {
        #pragma unroll
        for (int ms = 0; ms < 2; ++ms)
            #pragma unroll
            for (int i = 0; i < 4; ++i)
                PLs[(size_t)z * NROWS + r0 + ms*16 + lhi*4 + i] = lpart[ms][i];
    }
    const size_t zo = (size_t)z * NROWS * 64;
    #pragma unroll
    for (int ms = 0; ms < 2; ++ms)
        #pragma unroll
        for (int d = 0; d < 4; ++d) {
            const int col = d*16 + l16;
            #pragma unroll
            for (int i = 0; i < 4; ++i) {
                const size_t off = zo + (size_t)(r0 + ms*16 + lhi*4 + i) * 64 + col;
                POR[off] = oR[ms][d][i];
                POP[off] = oP[ms][d][i];
            }
        }
}

// ---- combine KV-split partials, normalize, write [B,S,D] bf16 (x4 vectorized) ----
__global__ __launch_bounds__(256) void merge_kernel(
    const float* __restrict__ POR, const float* __restrict__ POP,
    const float* __restrict__ PLs, int nsp,
    bf16* __restrict__ Xr, bf16* __restrict__ Xp)
{
    const int idx = blockIdx.x * 256 + threadIdx.x;   // 0 .. NROWS*16-1
    const int r = idx >> 4, c0 = (idx & 15) * 4;
    float l = 0.f;
    f32x4 orv = {}, opv = {};
    for (int zz = 0; zz < nsp; ++zz) {
        l += PLs[(size_t)zz * NROWS + r];
        const size_t o = (size_t)zz * NROWS * 64 + (size_t)r * 64 + c0;
        orv += *reinterpret_cast<const f32x4*>(&POR[o]);
        opv += *reinterpret_cast<const f32x4*>(&POP[o]);
    }
    const float inv = 1.f / l;
    const int bh = r >> 11, q = r & 2047;
    const int b = bh >> 3, h = bh & 7;
    const size_t off = ((size_t)(b*CS + q)) * CD + h*CDK + c0;
    bf16 vr[4], vp[4];
    #pragma unroll
    for (int j = 0; j < 4; ++j) { vr[j] = (bf16)(orv[j]*inv); vp[j] = (bf16)(opv[j]*inv); }
    *reinterpret_cast<uint2*>(&Xr[off]) = *reinterpret_cast<const uint2*>(vr);
    *reinterpret_cast<uint2*>(&Xp[off]) = *reinterpret_cast<const uint2*>(vp);
}

extern "C" void kernel_launch(void* const* d_in, const int* in_sizes, int n_in,
                              void* d_out, int out_size, void* d_ws, size_t ws_size,
                              hipStream_t stream) {
    const float* q_r = (const float*)d_in[0];
    const float* k_r = (const float*)d_in[1];
    const float* v_r = (const float*)d_in[2];
    const float* q_p = (const float*)d_in[3];
    const float* k_p = (const float*)d_in[4];
    const float* v_p = (const float*)d_in[5];
    const int*  mask = (const int*)d_in[6];
    const float* Wq = (const float*)d_in[7];  const float* bq = (const float*)d_in[8];
    const float* Wk = (const float*)d_in[9];  const float* bk = (const float*)d_in[10];
    const float* Wv = (const float*)d_in[11]; const float* bv = (const float*)d_in[12];
    const float* Wo = (const float*)d_in[13]; const float* bo = (const float*)d_in[14];
    float* out = (float*)d_out;

    bf16* ws = (bf16*)d_ws;
    bf16 *Qr = ws,        *Qp = Qr + NT;
    bf16 *Kr = Qp + NT,   *Kp = Kr + NT;
    bf16 *Vtr = Kp + NT,  *Vtp = Vtr + NT;
    bf16 *Xr = Vtp + NT,  *Xp = Xr + NT;     // 8 * NT * 2B = 33.55 MB
    float* POR = (float*)(ws + 8 * NT);

    const size_t fixed = 8 * NT * sizeof(bf16);
    const size_t per_split = (size_t)NROWS * 64 * 4 * 2 + (size_t)NROWS * 4;
    int nsp, lognsp;
    if (ws_size >= fixed + 2 * per_split) { nsp = 2; lognsp = 1; }
    else                                  { nsp = 1; lognsp = 0; }
    float* POP = POR + (size_t)nsp * NROWS * 64;
    float* PLs = POP + (size_t)nsp * NROWS * 64;

    dim3 blk(256);

    PPtrs P;
    P.A[0]=q_r; P.A[1]=q_p; P.A[2]=k_r; P.A[3]=k_p; P.A[4]=v_r; P.A[5]=v_p;
    P.W[0]=Wq;  P.W[1]=Wq;  P.W[2]=Wk;  P.W[3]=Wk;  P.W[4]=Wv;  P.W[5]=Wv;
    P.bias[0]=bq; P.bias[1]=bq; P.bias[2]=bk; P.bias[3]=bk; P.bias[4]=bv; P.bias[5]=bv;
    P.dst[0]=Qr; P.dst[1]=Qp; P.dst[2]=Kr; P.dst[3]=Kp; P.dst[4]=Vtr; P.dst[5]=Vtp;
    P.mode[0]=0; P.mode[1]=0; P.mode[2]=0; P.mode[3]=0; P.mode[4]=1; P.mode[5]=1;

    proj_kernel<<<dim3(32, 4, 6), blk, 0, stream>>>(P);

    attn_kernel<<<dim3(256 * nsp), blk, 0, stream>>>(Qr, Qp, Kr, Kp, Vtr, Vtp,
                                                     mask, lognsp, POR, POP, PLs);

    merge_kernel<<<dim3(NROWS * 16 / 256), blk, 0, stream>>>(POR, POP, PLs, nsp, Xr, Xp);

    oproj_kernel<<<dim3(32, 4, 2), blk, 0, stream>>>(Xr, Xp, Wo, bo, out);
}